// Round 12
// baseline (740.434 us; speedup 1.0000x reference)
//
#include <hip/hip_runtime.h>
#include <hip/hip_bf16.h>
#include <stdint.h>

// Problem constants: B=2, T=2048, D=1024, H=16, HD=64
#define B_  2
#define T_  2048
#define D_  1024
#define H_  16
#define HD_ 64

typedef __bf16 bf16x8 __attribute__((ext_vector_type(8)));
typedef __bf16 bf16x4 __attribute__((ext_vector_type(4)));
typedef float  f32x4  __attribute__((ext_vector_type(4)));

__device__ __forceinline__ void async_copy16(const void* g, void* l) {
  __builtin_amdgcn_global_load_lds((__attribute__((address_space(1))) void*)(g),
                                   (__attribute__((address_space(3))) void*)(l),
                                   16, 0, 0);
}

// Device-scope grid barrier (megakernel phase fence).
// Safe because ALL blocks are co-resident: grid 512, capacity >= 4 blocks/CU
// (LDS 32768 -> 4/CU; launch_bounds(256,4) caps VGPR at 128 -> 4 waves/SIMD).
// Agent-scope acq/rel atomics + threadfence handle per-XCD L2 non-coherence.
__device__ __forceinline__ void gridbar(int* c, int target) {
  __syncthreads();
  __threadfence();
  if (threadIdx.x == 0) {
    __hip_atomic_fetch_add(c, 1, __ATOMIC_RELEASE, __HIP_MEMORY_SCOPE_AGENT);
    while (__hip_atomic_load(c, __ATOMIC_ACQUIRE, __HIP_MEMORY_SCOPE_AGENT) < target)
      __builtin_amdgcn_s_sleep(8);
  }
  __syncthreads();
  __threadfence();
}

// ---------------------------------------------------------------------------
// Phase bodies — byte-proven R10 code (169.4us best), blockIdx -> unit param.
// ---------------------------------------------------------------------------

// prep v2: unit<1024 = weight 64x64 transpose tile; unit>=1024 = x convert.
__device__ __forceinline__ void prep_body(int unit, int tid, unsigned char* smem,
                                          const float* __restrict__ x,
                                          const float* __restrict__ wq, const float* __restrict__ wk,
                                          const float* __restrict__ wv, const float* __restrict__ wo,
                                          __bf16* __restrict__ xc,
                                          __bf16* __restrict__ wqkv_t, __bf16* __restrict__ wo_t) {
  if (unit < 1024) {
    __bf16 (*tile)[68] = (__bf16(*)[68])smem;      // 64x68 bf16 = 8704B
    const int z   = unit >> 8;
    const int rem = unit & 255;
    const int n0 = (rem & 15) * 64, k0 = (rem >> 4) * 64;
    const int kl = tid >> 4;
    const int nn = (tid & 15) * 4;
    const float* src = (z == 0) ? wq : (z == 1) ? wk : (z == 2) ? wv : wo;
    __bf16* dst = (z < 3) ? (wqkv_t + (size_t)z * 1024 * 1024) : wo_t;
#pragma unroll
    for (int it = 0; it < 4; ++it) {
      const int k = it * 16 + kl;
      const f32x4 v = *(const f32x4*)(src + (size_t)(k0 + k) * 1024 + n0 + nn);
      bf16x4 bv;
#pragma unroll
      for (int j = 0; j < 4; ++j) bv[j] = (__bf16)v[j];
      *(bf16x4*)&tile[k][nn] = bv;
    }
    __syncthreads();
#pragma unroll
    for (int it = 0; it < 4; ++it) {
      const int n = it * 16 + kl;
      bf16x4 bv;
#pragma unroll
      for (int j = 0; j < 4; ++j) bv[j] = tile[nn + j][n];
      *(bf16x4*)(dst + (size_t)(n0 + n) * 1024 + k0 + nn) = bv;
    }
    __syncthreads();   // tile reused by next unit of this block
  } else {
    const int i0 = ((unit - 1024) * 256 + tid) * 8;
    const f32x4 f0 = *(const f32x4*)(x + i0);
    const f32x4 f1 = *(const f32x4*)(x + i0 + 4);
    bf16x8 v;
#pragma unroll
    for (int k = 0; k < 4; ++k) { v[k] = (__bf16)f0[k]; v[k + 4] = (__bf16)f1[k]; }
    *(bf16x8*)(xc + i0) = v;
  }
}

// gemm128 (proven R5 structure + T1 swizzle), MODE by template.
template <int MODE>
__device__ __forceinline__ void gemm_body(int unit, int tid, unsigned char* smem,
                                          const __bf16* __restrict__ A, const __bf16* __restrict__ Bt,
                                          __bf16* __restrict__ q_b, __bf16* __restrict__ k_b,
                                          __bf16* __restrict__ vt_b,
                                          const float* __restrict__ bo, float* __restrict__ outp) {
  __bf16* As = (__bf16*)smem;            // 128*64
  __bf16* Bs = As + 8192;                // 128*64  (total 32768B)
  const int K = 1024;
  const int w    = tid >> 6, lane = tid & 63;
  const int quad = lane >> 4, lr = lane & 15;

  int bx, by;
  if (MODE == 0) {
    const int wgid = (unit & 7) * 96 + (unit >> 3);   // 768 units
    bx = wgid >> 5; by = wgid & 31;
  } else {
    const int wgid = (unit & 7) * 32 + (unit >> 3);   // 256 units
    bx = wgid & 7;  by = wgid >> 3;
  }
  const int tm = by * 128, tn = bx * 128;
  const int wm = (w >> 1) * 64, wn = (w & 1) * 64;
  const int lrow   = lane >> 3;
  const int gchunk = (lane & 7) ^ lrow;

  f32x4 acc[4][4] = {};

  for (int k0 = 0; k0 < K; k0 += 64) {
#pragma unroll
    for (int c = 0; c < 4; ++c) {
      const int chunk = w * 4 + c;
      const int row   = chunk * 8 + lrow;
      async_copy16(A  + (size_t)(tm + row) * K + k0 + gchunk * 8, As + chunk * 512);
      async_copy16(Bt + (size_t)(tn + row) * K + k0 + gchunk * 8, Bs + chunk * 512);
    }
    __syncthreads();
#pragma unroll
    for (int ks = 0; ks < 2; ++ks) {
      bf16x8 af[4], bfr[4];
#pragma unroll
      for (int mi = 0; mi < 4; ++mi) {
        const int row = wm + mi * 16 + lr;
        const int ch  = (ks * 4 + quad) ^ (row & 7);
        af[mi] = *(const bf16x8*)(As + row * 64 + ch * 8);
      }
#pragma unroll
      for (int ni = 0; ni < 4; ++ni) {
        const int row = wn + ni * 16 + lr;
        const int ch  = (ks * 4 + quad) ^ (row & 7);
        bfr[ni] = *(const bf16x8*)(Bs + row * 64 + ch * 8);
      }
#pragma unroll
      for (int mi = 0; mi < 4; ++mi)
#pragma unroll
        for (int ni = 0; ni < 4; ++ni)
          acc[mi][ni] = __builtin_amdgcn_mfma_f32_16x16x32_bf16(af[mi], bfr[ni], acc[mi][ni], 0, 0, 0);
    }
    __syncthreads();
  }

  if (MODE == 0) {
#pragma unroll
    for (int mi = 0; mi < 4; ++mi) {
      const int mrow0 = tm + wm + mi * 16 + quad * 4;
      const int b  = mrow0 >> 11;
      const int t0 = mrow0 & 2047;
#pragma unroll
      for (int ni = 0; ni < 4; ++ni) {
        const int ncol = tn + wn + ni * 16 + lr;
        const int mat  = ncol >> 10;
        const int nn   = ncol & 1023;
        const int h = nn >> 6, hd = nn & 63;
        if (mat == 0) {
#pragma unroll
          for (int r = 0; r < 4; ++r)
            q_b[((size_t)((b * H_ + h) * T_ + t0 + r)) * HD_ + hd] =
                (__bf16)(acc[mi][ni][r] * 0.125f);
        } else if (mat == 1) {
#pragma unroll
          for (int r = 0; r < 4; ++r)
            k_b[((size_t)((b * H_ + h) * T_ + t0 + r)) * HD_ + hd] =
                (__bf16)(acc[mi][ni][r]);
        } else {
          bf16x4 pk;
#pragma unroll
          for (int r = 0; r < 4; ++r) pk[r] = (__bf16)(acc[mi][ni][r]);
          *(bf16x4*)(vt_b + ((size_t)(b * H_ + h) * HD_ + hd) * T_ + t0) = pk;
        }
      }
    }
  } else {
#pragma unroll
    for (int mi = 0; mi < 4; ++mi) {
      const int m0 = tm + wm + mi * 16 + quad * 4;
#pragma unroll
      for (int ni = 0; ni < 4; ++ni) {
        const int n = tn + wn + ni * 16 + lr;
        const float bias = bo[n];
#pragma unroll
        for (int r = 0; r < 4; ++r)
          outp[(size_t)(m0 + r) * D_ + n] = acc[mi][ni][r] + bias;
      }
    }
  }
}

// attn v11 (proven best): id-parametrized.
__device__ __forceinline__ void attn_body(int id, int tid, unsigned char* smem,
                                          const __bf16* __restrict__ q_b, const __bf16* __restrict__ k_b,
                                          const __bf16* __restrict__ vt_b, __bf16* __restrict__ ctx) {
  __bf16* sV = (__bf16*)smem;                        // 64*64 = 8192B
  __bf16 (*sP)[64][72] = (__bf16(*)[64][72])(smem + 8192);  // 2*64*72*2 = 18432B
  const int w    = tid >> 6, lane = tid & 63;
  const int quad = lane >> 4, lr = lane & 15;
  const int bh  = (id & 7) * 4 + ((id >> 3) & 3);
  const int t0i = (id >> 5) & 7;
  const int rnd = id >> 8;
  const int tq  = (3 - rnd) * 8 + ((rnd & 1) ? t0i : (7 - t0i));
  const __bf16* qh = q_b  + (size_t)bh * T_ * HD_;
  const __bf16* kh = k_b  + (size_t)bh * T_ * HD_;
  const __bf16* vh = vt_b + (size_t)bh * HD_ * T_;
  const int b = bh >> 4, h = bh & 15;

  const int r0 = tid >> 3, r1 = (tid + 256) >> 3;
  const int g0 = tid & 7;

  const int q0 = tq * 64;
  const int nj = tq + 1;
  const int w16 = w * 16;

  bf16x8 qf[4][2];
#pragma unroll
  for (int qs = 0; qs < 4; ++qs)
#pragma unroll
    for (int ks = 0; ks < 2; ++ks)
      qf[qs][ks] = *(const bf16x8*)(qh + (size_t)(q0 + qs * 16 + lr) * HD_ + ks * 32 + quad * 8);

  bf16x8 onesf;
#pragma unroll
  for (int j = 0; j < 8; ++j) onesf[j] = (__bf16)1.0f;

  f32x4 o[4] = {};
  f32x4 ls = {};

  const __bf16* kr = kh + (size_t)(w16 + lr) * HD_;
  bf16x8 kf0 = *(const bf16x8*)(kr + quad * 8);
  bf16x8 kf1 = *(const bf16x8*)(kr + 32 + quad * 8);
  bf16x8 kn0, kn1;

  bf16x8 vr0 = *(const bf16x8*)(vh + (size_t)r0 * T_ + g0 * 8);
  bf16x8 vr1 = *(const bf16x8*)(vh + (size_t)r1 * T_ + g0 * 8);

  for (int j = 0; j < nj; ++j) {
    const int j0 = j * 64;
    const int pb = j & 1;
    __syncthreads();
    *(bf16x8*)(sV + r0 * 64 + (g0 ^ (r0 & 7)) * 8) = vr0;
    *(bf16x8*)(sV + r1 * 64 + (g0 ^ (r1 & 7)) * 8) = vr1;
    __syncthreads();
    if (j + 1 < nj) {
      const int jn = j0 + 64;
      vr0 = *(const bf16x8*)(vh + (size_t)r0 * T_ + jn + g0 * 8);
      vr1 = *(const bf16x8*)(vh + (size_t)r1 * T_ + jn + g0 * 8);
      kn0 = *(const bf16x8*)(kr + (size_t)jn * HD_ + quad * 8);
      kn1 = *(const bf16x8*)(kr + (size_t)jn * HD_ + 32 + quad * 8);
    }
    f32x4 ns[4] = {};
    __builtin_amdgcn_s_setprio(1);
#pragma unroll
    for (int qb = 0; qb < 4; ++qb) {
      ns[qb] = __builtin_amdgcn_mfma_f32_16x16x32_bf16(kf0, qf[qb][0], ns[qb], 0, 0, 0);
      ns[qb] = __builtin_amdgcn_mfma_f32_16x16x32_bf16(kf1, qf[qb][1], ns[qb], 0, 0, 0);
    }
    __builtin_amdgcn_s_setprio(0);
    if (j + 1 < nj) { kf0 = kn0; kf1 = kn1; }
    if (j0 + 63 > q0) {
      const int kvb = j0 + w16 + quad * 4;
#pragma unroll
      for (int qb = 0; qb < 4; ++qb) {
        const int qg = q0 + qb * 16 + lr;
#pragma unroll
        for (int r = 0; r < 4; ++r)
          if (kvb + r > qg) ns[qb][r] = -3.0e38f;
      }
    }
#pragma unroll
    for (int qb = 0; qb < 4; ++qb)
#pragma unroll
      for (int r = 0; r < 4; ++r)
        ns[qb][r] = __expf(ns[qb][r]);
#pragma unroll
    for (int qb = 0; qb < 4; ++qb) {
      bf16x4 pk;
#pragma unroll
      for (int r = 0; r < 4; ++r) pk[r] = (__bf16)ns[qb][r];
      *(bf16x4*)(&sP[pb][qb * 16 + lr][w16 + quad * 4]) = pk;
    }
    __syncthreads();
    bf16x8 pf[2];
#pragma unroll
    for (int ks = 0; ks < 2; ++ks)
      pf[ks] = *(const bf16x8*)(&sP[pb][w16 + lr][ks * 32 + quad * 8]);
    __builtin_amdgcn_s_setprio(1);
#pragma unroll
    for (int ni = 0; ni < 4; ++ni) {
      const int row = ni * 16 + lr;
#pragma unroll
      for (int ks = 0; ks < 2; ++ks) {
        const int ch = (ks * 4 + quad) ^ (row & 7);
        bf16x8 vf = *(const bf16x8*)(sV + row * 64 + ch * 8);
        o[ni] = __builtin_amdgcn_mfma_f32_16x16x32_bf16(pf[ks], vf, o[ni], 0, 0, 0);
      }
    }
    ls = __builtin_amdgcn_mfma_f32_16x16x32_bf16(pf[0], onesf, ls, 0, 0, 0);
    ls = __builtin_amdgcn_mfma_f32_16x16x32_bf16(pf[1], onesf, ls, 0, 0, 0);
    __builtin_amdgcn_s_setprio(0);
  }
#pragma unroll
  for (int r = 0; r < 4; ++r) {
    const float inv = 1.0f / ls[r];
    const int t = q0 + w16 + quad * 4 + r;
#pragma unroll
    for (int ni = 0; ni < 4; ++ni)
      ctx[((size_t)(b * T_ + t)) * D_ + h * HD_ + ni * 16 + lr] =
          (__bf16)(o[ni][r] * inv);
  }
  __syncthreads();   // smem reused by this block's next attn unit
}

// ---------------------------------------------------------------------------
// Megakernel: {prep -> gemm0 -> attn -> gemm1} with 3 atomic grid barriers.
// Removes 3 kernel-launch boundaries (R11 audit: kernel-sum ~100us vs total
// ~170us -> ~20-30us of launch/serialization gaps on top of the harness fill).
// Grid 512 x 256thr; all blocks co-resident (see gridbar comment).
// Unit maps: prep 6/block (3072); gemm0 {b, 512+b|b<256} (768); attn {2b,2b+1}
// (1024, same tq twice = balanced); gemm1 b<256 (256).
// ---------------------------------------------------------------------------
__launch_bounds__(256, 4)
__global__ void mega_kernel(const float* __restrict__ x,
                            const float* __restrict__ wq, const float* __restrict__ wk,
                            const float* __restrict__ wv, const float* __restrict__ wo,
                            const float* __restrict__ bo, float* __restrict__ outp,
                            __bf16* __restrict__ xc,
                            __bf16* __restrict__ wqkv_t, __bf16* __restrict__ wo_t,
                            __bf16* __restrict__ q_b, __bf16* __restrict__ k_b,
                            __bf16* __restrict__ vt_b, __bf16* __restrict__ ctx,
                            int* __restrict__ bar) {
  __shared__ __align__(16) unsigned char smem[32768];
  const int blk = blockIdx.x;
  const int tid = threadIdx.x;

  // phase 0: prep (6 units per block)
#pragma unroll 1
  for (int u = 0; u < 6; ++u)
    prep_body(blk * 6 + u, tid, smem, x, wq, wk, wv, wo, xc, wqkv_t, wo_t);
  gridbar(&bar[0], 512);

  // phase 1: QKV projection GEMM (768 units)
  gemm_body<0>(blk, tid, smem, xc, wqkv_t, q_b, k_b, vt_b, nullptr, nullptr);
  if (blk < 256)
    gemm_body<0>(512 + blk, tid, smem, xc, wqkv_t, q_b, k_b, vt_b, nullptr, nullptr);
  gridbar(&bar[1], 512);

  // phase 2: attention (1024 units, 2 per block, same tq = balanced)
  attn_body(2 * blk,     tid, smem, q_b, k_b, vt_b, ctx);
  attn_body(2 * blk + 1, tid, smem, q_b, k_b, vt_b, ctx);
  gridbar(&bar[2], 512);

  // phase 3: output projection GEMM (256 units)
  if (blk < 256)
    gemm_body<1>(blk, tid, smem, ctx, wo_t, nullptr, nullptr, nullptr, bo, outp);
}

// ---------------------------------------------------------------------------
extern "C" void kernel_launch(void* const* d_in, const int* in_sizes, int n_in,
                              void* d_out, int out_size, void* d_ws, size_t ws_size,
                              hipStream_t stream) {
  (void)in_sizes; (void)n_in; (void)out_size; (void)ws_size;
  const float* x  = (const float*)d_in[0];
  const float* wq = (const float*)d_in[1];
  const float* wk = (const float*)d_in[2];
  const float* wv = (const float*)d_in[3];
  const float* wo = (const float*)d_in[4];
  const float* bo = (const float*)d_in[5];
  float* outp = (float*)d_out;

  char* ws = (char*)d_ws;
  __bf16* ctx    = (__bf16*)(ws + 0);           // [4096][1024] = 8 MB
  __bf16* wqkv_t = (__bf16*)(ws + 0);           // NOTE: moved — see below
  __bf16* wo_t   = (__bf16*)(ws + 8388608);     // 1024x1024 = 2 MB
  __bf16* q_b    = (__bf16*)(ws + 10485760);    // [2][16][2048][64] = 8 MB
  __bf16* k_b    = (__bf16*)(ws + 18874368);    // 8 MB
  __bf16* vt_b   = (__bf16*)(ws + 27262976);    // [2][16][64][2048] = 8 MB
  __bf16* xc     = (__bf16*)(ws + 35651584);    // canonical bf16 x = 8 MB
  // wqkv_t must now outlive prep->gemm0 within one kernel while ctx is only
  // written in attn (phase 2), after gemm0 is done with wqkv_t -> the old
  // aliasing (ctx == wqkv_t) is STILL safe: ctx writes happen in phase 2,
  // all wqkv_t reads end at the phase-1 barrier.
  int* bar = (int*)(ws + (size_t)128 * 1024 * 1024);  // counters in unused ws

  hipMemsetAsync(bar, 0, 256, stream);
  mega_kernel<<<512, 256, 0, stream>>>(x, wq, wk, wv, wo, bo, outp,
                                       xc, wqkv_t, wo_t, q_b, k_b, vt_b, ctx, bar);
}

// Round 13
// 169.634 us; speedup vs baseline: 4.3649x; 4.3649x over previous
//
#include <hip/hip_runtime.h>
#include <hip/hip_bf16.h>
#include <stdint.h>

// Problem constants: B=2, T=2048, D=1024, H=16, HD=64
#define B_  2
#define T_  2048
#define D_  1024
#define H_  16
#define HD_ 64

typedef __bf16 bf16x8 __attribute__((ext_vector_type(8)));
typedef __bf16 bf16x4 __attribute__((ext_vector_type(4)));
typedef float  f32x4  __attribute__((ext_vector_type(4)));

__device__ __forceinline__ void async_copy16(const void* g, void* l) {
  __builtin_amdgcn_global_load_lds((__attribute__((address_space(1))) void*)(g),
                                   (__attribute__((address_space(3))) void*)(l),
                                   16, 0, 0);
}

// ---------------------------------------------------------------------------
// Fused prep v2 (R10-measured, −2.9us vs v1):
//   blocks [0,1024):    transpose+convert the four 1024x1024 fp32 weights to
//                       bf16 (64x64 tiles, f32x4 reads, 128B coalesced writes)
//   blocks [1024,3072): convert x fp32 -> bf16, 8 elems/thread
// ---------------------------------------------------------------------------
__global__ void prep_kernel(const float* __restrict__ x,
                            const float* __restrict__ wq, const float* __restrict__ wk,
                            const float* __restrict__ wv, const float* __restrict__ wo,
                            __bf16* __restrict__ xc,
                            __bf16* __restrict__ wqkv_t, __bf16* __restrict__ wo_t) {
  const int id  = blockIdx.x;
  const int tid = threadIdx.x;
  if (id < 1024) {
    __shared__ __bf16 tile[64][68];                // pitch 68: 8B-aligned rows
    const int z   = id >> 8;                       // 0..3: wq,wk,wv,wo
    const int rem = id & 255;                      // 16x16 tiles of 64x64
    const int n0 = (rem & 15) * 64, k0 = (rem >> 4) * 64;
    const int kl = tid >> 4;                       // 0..15
    const int nn = (tid & 15) * 4;                 // 0,4,..,60
    const float* src = (z == 0) ? wq : (z == 1) ? wk : (z == 2) ? wv : wo;
    __bf16* dst = (z < 3) ? (wqkv_t + (size_t)z * 1024 * 1024) : wo_t;
#pragma unroll
    for (int it = 0; it < 4; ++it) {
      const int k = it * 16 + kl;
      const f32x4 v = *(const f32x4*)(src + (size_t)(k0 + k) * 1024 + n0 + nn);
      bf16x4 bv;
#pragma unroll
      for (int j = 0; j < 4; ++j) bv[j] = (__bf16)v[j];
      *(bf16x4*)&tile[k][nn] = bv;                 // 8B vector LDS write
    }
    __syncthreads();
#pragma unroll
    for (int it = 0; it < 4; ++it) {
      const int n = it * 16 + kl;                  // output row (n-index)
      bf16x4 bv;
#pragma unroll
      for (int j = 0; j < 4; ++j) bv[j] = tile[nn + j][n];
      // 16 lanes x 8B = 128B contiguous per output row
      *(bf16x4*)(dst + (size_t)(n0 + n) * 1024 + k0 + nn) = bv;
    }
  } else {
    const int i0 = ((id - 1024) * 256 + tid) * 8;
    const f32x4 f0 = *(const f32x4*)(x + i0);
    const f32x4 f1 = *(const f32x4*)(x + i0 + 4);
    bf16x8 v;
#pragma unroll
    for (int k = 0; k < 4; ++k) { v[k] = (__bf16)f0[k]; v[k + 4] = (__bf16)f1[k]; }
    *(bf16x8*)(xc + i0) = v;                       // 16B store
  }
}

// ---------------------------------------------------------------------------
// 128x128-tile bf16 MFMA GEMM, async global_load_lds staging — PROVEN (R5,
// in the best totals). T1 XCD-aware bijective grid swizzle:
//   MODE 0: grid 768; each XCD owns 3 full B-panel columns (768KB < 4MB L2).
//   MODE 1: grid 256; each XCD sees full wo_t (2MB) + A chunk.
// MODE 0 epilogue scatters Q (x0.125) / K to [b,h,t,hd], V^T to [b,h,hd,t].
// MODE 1 epilogue adds bias (fp32), stores fp32 to out.
// ---------------------------------------------------------------------------
template <int MODE>
__launch_bounds__(256)
__global__ void gemm128_kernel(const __bf16* __restrict__ A, const __bf16* __restrict__ Bt, int K,
                               __bf16* __restrict__ q_b, __bf16* __restrict__ k_b,
                               __bf16* __restrict__ vt_b,
                               const float* __restrict__ bo, float* __restrict__ outp) {
  __shared__ __align__(16) __bf16 As[128 * 64];
  __shared__ __align__(16) __bf16 Bs[128 * 64];
  const int tid  = threadIdx.x;
  const int w    = tid >> 6, lane = tid & 63;
  const int quad = lane >> 4, lr = lane & 15;

  const int orig = blockIdx.x;
  int bx, by;
  if (MODE == 0) {
    const int wgid = (orig & 7) * 96 + (orig >> 3);   // 768 blocks
    bx = wgid >> 5;            // 0..23  (N columns, 3 per XCD)
    by = wgid & 31;            // 0..31
  } else {
    const int wgid = (orig & 7) * 32 + (orig >> 3);   // 256 blocks
    bx = wgid & 7;             // 0..7
    by = wgid >> 3;            // 0..31
  }
  const int tm = by * 128, tn = bx * 128;
  const int wm = (w >> 1) * 64, wn = (w & 1) * 64;
  const int lrow   = lane >> 3;
  const int gchunk = (lane & 7) ^ lrow;

  f32x4 acc[4][4] = {};

  for (int k0 = 0; k0 < K; k0 += 64) {
#pragma unroll
    for (int c = 0; c < 4; ++c) {
      const int chunk = w * 4 + c;             // wave-uniform LDS base
      const int row   = chunk * 8 + lrow;
      async_copy16(A  + (size_t)(tm + row) * K + k0 + gchunk * 8, As + chunk * 512);
      async_copy16(Bt + (size_t)(tn + row) * K + k0 + gchunk * 8, Bs + chunk * 512);
    }
    __syncthreads();
#pragma unroll
    for (int ks = 0; ks < 2; ++ks) {
      bf16x8 af[4], bfr[4];
#pragma unroll
      for (int mi = 0; mi < 4; ++mi) {
        const int row = wm + mi * 16 + lr;
        const int ch  = (ks * 4 + quad) ^ (row & 7);
        af[mi] = *(const bf16x8*)(As + row * 64 + ch * 8);
      }
#pragma unroll
      for (int ni = 0; ni < 4; ++ni) {
        const int row = wn + ni * 16 + lr;
        const int ch  = (ks * 4 + quad) ^ (row & 7);
        bfr[ni] = *(const bf16x8*)(Bs + row * 64 + ch * 8);
      }
#pragma unroll
      for (int mi = 0; mi < 4; ++mi)
#pragma unroll
        for (int ni = 0; ni < 4; ++ni)
          acc[mi][ni] = __builtin_amdgcn_mfma_f32_16x16x32_bf16(af[mi], bfr[ni], acc[mi][ni], 0, 0, 0);
    }
    __syncthreads();
  }

  if (MODE == 0) {
#pragma unroll
    for (int mi = 0; mi < 4; ++mi) {
      const int mrow0 = tm + wm + mi * 16 + quad * 4;
      const int b  = mrow0 >> 11;
      const int t0 = mrow0 & 2047;
#pragma unroll
      for (int ni = 0; ni < 4; ++ni) {
        const int ncol = tn + wn + ni * 16 + lr;
        const int mat  = ncol >> 10;
        const int nn   = ncol & 1023;
        const int h = nn >> 6, hd = nn & 63;
        if (mat == 0) {
#pragma unroll
          for (int r = 0; r < 4; ++r)
            q_b[((size_t)((b * H_ + h) * T_ + t0 + r)) * HD_ + hd] =
                (__bf16)(acc[mi][ni][r] * 0.125f);
        } else if (mat == 1) {
#pragma unroll
          for (int r = 0; r < 4; ++r)
            k_b[((size_t)((b * H_ + h) * T_ + t0 + r)) * HD_ + hd] =
                (__bf16)(acc[mi][ni][r]);
        } else {
          bf16x4 pk;
#pragma unroll
          for (int r = 0; r < 4; ++r) pk[r] = (__bf16)(acc[mi][ni][r]);
          *(bf16x4*)(vt_b + ((size_t)(b * H_ + h) * HD_ + hd) * T_ + t0) = pk;
        }
      }
    }
  } else {
#pragma unroll
    for (int mi = 0; mi < 4; ++mi) {
      const int m0 = tm + wm + mi * 16 + quad * 4;
#pragma unroll
      for (int ni = 0; ni < 4; ++ni) {
        const int n = tn + wn + ni * 16 + lr;
        const float bias = bo[n];
#pragma unroll
        for (int r = 0; r < 4; ++r)
          outp[(size_t)(m0 + r) * D_ + n] = acc[mi][ni][r] + bias;
      }
    }
  }
}

// ---------------------------------------------------------------------------
// Flash attention v11 (causal) — EXACT R6/R10 code (best measured totals),
// __launch_bounds__(256,3) (R9 showed occ-4 is neutral; keep best-measured).
// K-split QK^T (wave w owns keys w*16..+15, swapped-operand MFMA S^T),
// K direct-to-reg ping-pong, V staged in XOR-swizzled LDS, block-shared
// sP[2] P^T exchange with b64 writes, ones-MFMA row sums, XCD head clustering.
// ---------------------------------------------------------------------------
__launch_bounds__(256, 3)
__global__ void attn_kernel(const __bf16* __restrict__ q_b, const __bf16* __restrict__ k_b,
                            const __bf16* __restrict__ vt_b, __bf16* __restrict__ ctx) {
  __shared__ __align__(16) __bf16 sV[64 * 64];      // [hd][kv] XOR-swizzled
  __shared__ __align__(16) __bf16 sP[2][64][72];    // block-shared dbuf P^T tile
  const int tid  = threadIdx.x;
  const int w    = tid >> 6, lane = tid & 63;
  const int quad = lane >> 4, lr = lane & 15;
  const int id = blockIdx.x;
  const int bh  = (id & 7) * 4 + ((id >> 3) & 3);   // XCD-clustered head
  const int t0i = (id >> 5) & 7;                    // slot within round
  const int rnd = id >> 8;                          // round 0..3 (heavy first)
  const int tq  = (3 - rnd) * 8 + ((rnd & 1) ? t0i : (7 - t0i));
  const __bf16* qh = q_b  + (size_t)bh * T_ * HD_;
  const __bf16* kh = k_b  + (size_t)bh * T_ * HD_;
  const __bf16* vh = vt_b + (size_t)bh * HD_ * T_;
  const int b = bh >> 4, h = bh & 15;

  const int r0 = tid >> 3, r1 = (tid + 256) >> 3;   // V staging rows (0..63)
  const int g0 = tid & 7;                           // chunk-in-row

  const int q0 = tq * 64;                           // block's 64-row Q tile
  const int nj = tq + 1;
  const int w16 = w * 16;

  bf16x8 qf[4][2];
#pragma unroll
  for (int qs = 0; qs < 4; ++qs)
#pragma unroll
    for (int ks = 0; ks < 2; ++ks)
      qf[qs][ks] = *(const bf16x8*)(qh + (size_t)(q0 + qs * 16 + lr) * HD_ + ks * 32 + quad * 8);

  bf16x8 onesf;
#pragma unroll
  for (int j = 0; j < 8; ++j) onesf[j] = (__bf16)1.0f;

  f32x4 o[4] = {};
  f32x4 ls = {};

  // K slice for this wave, iter 0 (direct to regs; ping-pong prefetched)
  const __bf16* kr = kh + (size_t)(w16 + lr) * HD_;
  bf16x8 kf0 = *(const bf16x8*)(kr + quad * 8);
  bf16x8 kf1 = *(const bf16x8*)(kr + 32 + quad * 8);
  bf16x8 kn0, kn1;

  // V tile j=0 prefetch into registers
  bf16x8 vr0 = *(const bf16x8*)(vh + (size_t)r0 * T_ + g0 * 8);
  bf16x8 vr1 = *(const bf16x8*)(vh + (size_t)r1 * T_ + g0 * 8);

  for (int j = 0; j < nj; ++j) {
    const int j0 = j * 64;
    const int pb = j & 1;
    __syncthreads();   // all waves done reading sV (and sP[pb]) from prev
    *(bf16x8*)(sV + r0 * 64 + (g0 ^ (r0 & 7)) * 8) = vr0;
    *(bf16x8*)(sV + r1 * 64 + (g0 ^ (r1 & 7)) * 8) = vr1;
    __syncthreads();
    if (j + 1 < nj) {   // overlap next-tile global loads with compute
      const int jn = j0 + 64;
      vr0 = *(const bf16x8*)(vh + (size_t)r0 * T_ + jn + g0 * 8);
      vr1 = *(const bf16x8*)(vh + (size_t)r1 * T_ + jn + g0 * 8);
      kn0 = *(const bf16x8*)(kr + (size_t)jn * HD_ + quad * 8);
      kn1 = *(const bf16x8*)(kr + (size_t)jn * HD_ + 32 + quad * 8);
    }
    // S^T = K (Q/8)^T for this wave's 16 kv rows x all 64 q (swapped MFMA)
    f32x4 ns[4] = {};
    __builtin_amdgcn_s_setprio(1);
#pragma unroll
    for (int qb = 0; qb < 4; ++qb) {
      ns[qb] = __builtin_amdgcn_mfma_f32_16x16x32_bf16(kf0, qf[qb][0], ns[qb], 0, 0, 0);
      ns[qb] = __builtin_amdgcn_mfma_f32_16x16x32_bf16(kf1, qf[qb][1], ns[qb], 0, 0, 0);
    }
    __builtin_amdgcn_s_setprio(0);
    if (j + 1 < nj) { kf0 = kn0; kf1 = kn1; }
    // causal mask (last j only): lane holds kv=j0+w16+quad*4+r, q=q0+qb*16+lr
    if (j0 + 63 > q0) {
      const int kvb = j0 + w16 + quad * 4;
#pragma unroll
      for (int qb = 0; qb < 4; ++qb) {
        const int qg = q0 + qb * 16 + lr;
#pragma unroll
        for (int r = 0; r < 4; ++r)
          if (kvb + r > qg) ns[qb][r] = -3.0e38f;
      }
    }
    // static-base softmax: P = exp(s)
#pragma unroll
    for (int qb = 0; qb < 4; ++qb)
#pragma unroll
      for (int r = 0; r < 4; ++r)
        ns[qb][r] = __expf(ns[qb][r]);
    // scatter P^T into block-shared sP: 4 kv-contiguous values -> b64 writes
#pragma unroll
    for (int qb = 0; qb < 4; ++qb) {
      bf16x4 pk;
#pragma unroll
      for (int r = 0; r < 4; ++r) pk[r] = (__bf16)ns[qb][r];
      *(bf16x4*)(&sP[pb][qb * 16 + lr][w16 + quad * 4]) = pk;
    }
    __syncthreads();   // all waves' P columns visible
    bf16x8 pf[2];
#pragma unroll
    for (int ks = 0; ks < 2; ++ks)
      pf[ks] = *(const bf16x8*)(&sP[pb][w16 + lr][ks * 32 + quad * 8]);
    // O += P * V  (V^T from LDS: row = hd, cols = kv); row sums via ones-MFMA
    __builtin_amdgcn_s_setprio(1);
#pragma unroll
    for (int ni = 0; ni < 4; ++ni) {
      const int row = ni * 16 + lr;
#pragma unroll
      for (int ks = 0; ks < 2; ++ks) {
        const int ch = (ks * 4 + quad) ^ (row & 7);
        bf16x8 vf = *(const bf16x8*)(sV + row * 64 + ch * 8);
        o[ni] = __builtin_amdgcn_mfma_f32_16x16x32_bf16(pf[ks], vf, o[ni], 0, 0, 0);
      }
    }
    ls = __builtin_amdgcn_mfma_f32_16x16x32_bf16(pf[0], onesf, ls, 0, 0, 0);
    ls = __builtin_amdgcn_mfma_f32_16x16x32_bf16(pf[1], onesf, ls, 0, 0, 0);
    __builtin_amdgcn_s_setprio(0);
  }
  // normalize and store ctx in merged [b*T+t][h*64+d] layout (bf16).
  // ls[r] = rowsum for q = q0 + w16 + quad*4 + r (replicated over lr).
#pragma unroll
  for (int r = 0; r < 4; ++r) {
    const float inv = 1.0f / ls[r];
    const int t = q0 + w16 + quad * 4 + r;
#pragma unroll
    for (int ni = 0; ni < 4; ++ni)
      ctx[((size_t)(b * T_ + t)) * D_ + h * HD_ + ni * 16 + lr] =
          (__bf16)(o[ni][r] * inv);
  }
}

// ---------------------------------------------------------------------------
extern "C" void kernel_launch(void* const* d_in, const int* in_sizes, int n_in,
                              void* d_out, int out_size, void* d_ws, size_t ws_size,
                              hipStream_t stream) {
  (void)in_sizes; (void)n_in; (void)out_size; (void)ws_size;
  const float* x  = (const float*)d_in[0];
  const float* wq = (const float*)d_in[1];
  const float* wk = (const float*)d_in[2];
  const float* wv = (const float*)d_in[3];
  const float* wo = (const float*)d_in[4];
  const float* bo = (const float*)d_in[5];
  float* outp = (float*)d_out;

  char* ws = (char*)d_ws;
  __bf16* ctx    = (__bf16*)(ws + 0);           // [4096][1024] = 8 MB
  __bf16* wqkv_t = (__bf16*)(ws + 0);           // 3072x1024 = 6 MB (dead after gemm<0>)
  __bf16* wo_t   = (__bf16*)(ws + 8388608);     // 1024x1024 = 2 MB
  __bf16* q_b    = (__bf16*)(ws + 10485760);    // [2][16][2048][64] = 8 MB
  __bf16* k_b    = (__bf16*)(ws + 18874368);    // 8 MB
  __bf16* vt_b   = (__bf16*)(ws + 27262976);    // [2][16][64][2048] = 8 MB
  __bf16* xc     = (__bf16*)(ws + 35651584);    // canonical bf16 x = 8 MB

  prep_kernel<<<3072, 256, 0, stream>>>(x, wq, wk, wv, wo, xc, wqkv_t, wo_t);
  gemm128_kernel<0><<<768, 256, 0, stream>>>(xc, wqkv_t, 1024, q_b, k_b, vt_b, nullptr, nullptr);
  attn_kernel<<<1024, 256, 0, stream>>>(q_b, k_b, vt_b, ctx);
  gemm128_kernel<1><<<256, 256, 0, stream>>>(ctx, wo_t, 1024, nullptr, nullptr, nullptr, bo, outp);
}

// Round 14
// 169.422 us; speedup vs baseline: 4.3704x; 1.0013x over previous
//
#include <hip/hip_runtime.h>
#include <hip/hip_bf16.h>
#include <stdint.h>

// Problem constants: B=2, T=2048, D=1024, H=16, HD=64
#define B_  2
#define T_  2048
#define D_  1024
#define H_  16
#define HD_ 64

typedef __bf16 bf16x8 __attribute__((ext_vector_type(8)));
typedef __bf16 bf16x4 __attribute__((ext_vector_type(4)));
typedef float  f32x4  __attribute__((ext_vector_type(4)));

__device__ __forceinline__ void async_copy16(const void* g, void* l) {
  __builtin_amdgcn_global_load_lds((__attribute__((address_space(1))) void*)(g),
                                   (__attribute__((address_space(3))) void*)(l),
                                   16, 0, 0);
}

// ---------------------------------------------------------------------------
// Fused prep v2 (R10-measured, −2.9us vs v1):
//   blocks [0,1024):    transpose+convert the four 1024x1024 fp32 weights to
//                       bf16 (64x64 tiles, f32x4 reads, 128B coalesced writes)
//   blocks [1024,3072): convert x fp32 -> bf16, 8 elems/thread
// ---------------------------------------------------------------------------
__global__ void prep_kernel(const float* __restrict__ x,
                            const float* __restrict__ wq, const float* __restrict__ wk,
                            const float* __restrict__ wv, const float* __restrict__ wo,
                            __bf16* __restrict__ xc,
                            __bf16* __restrict__ wqkv_t, __bf16* __restrict__ wo_t) {
  const int id  = blockIdx.x;
  const int tid = threadIdx.x;
  if (id < 1024) {
    __shared__ __bf16 tile[64][68];                // pitch 68: 8B-aligned rows
    const int z   = id >> 8;                       // 0..3: wq,wk,wv,wo
    const int rem = id & 255;                      // 16x16 tiles of 64x64
    const int n0 = (rem & 15) * 64, k0 = (rem >> 4) * 64;
    const int kl = tid >> 4;                       // 0..15
    const int nn = (tid & 15) * 4;                 // 0,4,..,60
    const float* src = (z == 0) ? wq : (z == 1) ? wk : (z == 2) ? wv : wo;
    __bf16* dst = (z < 3) ? (wqkv_t + (size_t)z * 1024 * 1024) : wo_t;
#pragma unroll
    for (int it = 0; it < 4; ++it) {
      const int k = it * 16 + kl;
      const f32x4 v = *(const f32x4*)(src + (size_t)(k0 + k) * 1024 + n0 + nn);
      bf16x4 bv;
#pragma unroll
      for (int j = 0; j < 4; ++j) bv[j] = (__bf16)v[j];
      *(bf16x4*)&tile[k][nn] = bv;                 // 8B vector LDS write
    }
    __syncthreads();
#pragma unroll
    for (int it = 0; it < 4; ++it) {
      const int n = it * 16 + kl;                  // output row (n-index)
      bf16x4 bv;
#pragma unroll
      for (int j = 0; j < 4; ++j) bv[j] = tile[nn + j][n];
      // 16 lanes x 8B = 128B contiguous per output row
      *(bf16x4*)(dst + (size_t)(n0 + n) * 1024 + k0 + nn) = bv;
    }
  } else {
    const int i0 = ((id - 1024) * 256 + tid) * 8;
    const f32x4 f0 = *(const f32x4*)(x + i0);
    const f32x4 f1 = *(const f32x4*)(x + i0 + 4);
    bf16x8 v;
#pragma unroll
    for (int k = 0; k < 4; ++k) { v[k] = (__bf16)f0[k]; v[k + 4] = (__bf16)f1[k]; }
    *(bf16x8*)(xc + i0) = v;                       // 16B store
  }
}

// ---------------------------------------------------------------------------
// 128x128-tile bf16 MFMA GEMM, async global_load_lds staging — PROVEN (R5,
// in the best totals). T1 XCD-aware bijective grid swizzle:
//   MODE 0: grid 768; each XCD owns 3 full B-panel columns (768KB < 4MB L2).
//   MODE 1: grid 256; each XCD sees full wo_t (2MB) + A chunk.
// MODE 0 epilogue scatters Q (x0.125) / K to [b,h,t,hd], V^T to [b,h,hd,t].
// MODE 1 epilogue adds bias (fp32), stores fp32 to out.
// ---------------------------------------------------------------------------
template <int MODE>
__launch_bounds__(256)
__global__ void gemm128_kernel(const __bf16* __restrict__ A, const __bf16* __restrict__ Bt, int K,
                               __bf16* __restrict__ q_b, __bf16* __restrict__ k_b,
                               __bf16* __restrict__ vt_b,
                               const float* __restrict__ bo, float* __restrict__ outp) {
  __shared__ __align__(16) __bf16 As[128 * 64];
  __shared__ __align__(16) __bf16 Bs[128 * 64];
  const int tid  = threadIdx.x;
  const int w    = tid >> 6, lane = tid & 63;
  const int quad = lane >> 4, lr = lane & 15;

  const int orig = blockIdx.x;
  int bx, by;
  if (MODE == 0) {
    const int wgid = (orig & 7) * 96 + (orig >> 3);   // 768 blocks
    bx = wgid >> 5;            // 0..23  (N columns, 3 per XCD)
    by = wgid & 31;            // 0..31
  } else {
    const int wgid = (orig & 7) * 32 + (orig >> 3);   // 256 blocks
    bx = wgid & 7;             // 0..7
    by = wgid >> 3;            // 0..31
  }
  const int tm = by * 128, tn = bx * 128;
  const int wm = (w >> 1) * 64, wn = (w & 1) * 64;
  const int lrow   = lane >> 3;
  const int gchunk = (lane & 7) ^ lrow;

  f32x4 acc[4][4] = {};

  for (int k0 = 0; k0 < K; k0 += 64) {
#pragma unroll
    for (int c = 0; c < 4; ++c) {
      const int chunk = w * 4 + c;             // wave-uniform LDS base
      const int row   = chunk * 8 + lrow;
      async_copy16(A  + (size_t)(tm + row) * K + k0 + gchunk * 8, As + chunk * 512);
      async_copy16(Bt + (size_t)(tn + row) * K + k0 + gchunk * 8, Bs + chunk * 512);
    }
    __syncthreads();
#pragma unroll
    for (int ks = 0; ks < 2; ++ks) {
      bf16x8 af[4], bfr[4];
#pragma unroll
      for (int mi = 0; mi < 4; ++mi) {
        const int row = wm + mi * 16 + lr;
        const int ch  = (ks * 4 + quad) ^ (row & 7);
        af[mi] = *(const bf16x8*)(As + row * 64 + ch * 8);
      }
#pragma unroll
      for (int ni = 0; ni < 4; ++ni) {
        const int row = wn + ni * 16 + lr;
        const int ch  = (ks * 4 + quad) ^ (row & 7);
        bfr[ni] = *(const bf16x8*)(Bs + row * 64 + ch * 8);
      }
#pragma unroll
      for (int mi = 0; mi < 4; ++mi)
#pragma unroll
        for (int ni = 0; ni < 4; ++ni)
          acc[mi][ni] = __builtin_amdgcn_mfma_f32_16x16x32_bf16(af[mi], bfr[ni], acc[mi][ni], 0, 0, 0);
    }
    __syncthreads();
  }

  if (MODE == 0) {
#pragma unroll
    for (int mi = 0; mi < 4; ++mi) {
      const int mrow0 = tm + wm + mi * 16 + quad * 4;
      const int b  = mrow0 >> 11;
      const int t0 = mrow0 & 2047;
#pragma unroll
      for (int ni = 0; ni < 4; ++ni) {
        const int ncol = tn + wn + ni * 16 + lr;
        const int mat  = ncol >> 10;
        const int nn   = ncol & 1023;
        const int h = nn >> 6, hd = nn & 63;
        if (mat == 0) {
#pragma unroll
          for (int r = 0; r < 4; ++r)
            q_b[((size_t)((b * H_ + h) * T_ + t0 + r)) * HD_ + hd] =
                (__bf16)(acc[mi][ni][r] * 0.125f);
        } else if (mat == 1) {
#pragma unroll
          for (int r = 0; r < 4; ++r)
            k_b[((size_t)((b * H_ + h) * T_ + t0 + r)) * HD_ + hd] =
                (__bf16)(acc[mi][ni][r]);
        } else {
          bf16x4 pk;
#pragma unroll
          for (int r = 0; r < 4; ++r) pk[r] = (__bf16)(acc[mi][ni][r]);
          *(bf16x4*)(vt_b + ((size_t)(b * H_ + h) * HD_ + hd) * T_ + t0) = pk;
        }
      }
    }
  } else {
#pragma unroll
    for (int mi = 0; mi < 4; ++mi) {
      const int m0 = tm + wm + mi * 16 + quad * 4;
#pragma unroll
      for (int ni = 0; ni < 4; ++ni) {
        const int n = tn + wn + ni * 16 + lr;
        const float bias = bo[n];
#pragma unroll
        for (int r = 0; r < 4; ++r)
          outp[(size_t)(m0 + r) * D_ + n] = acc[mi][ni][r] + bias;
      }
    }
  }
}

// ---------------------------------------------------------------------------
// Flash attention v15 (causal) = v11 (best measured) MINUS one barrier.
// Audit: v11 carried a barrier inherited from v10 between the sV writes and
// QK^T. In v10 it was required (QK read K from LDS staged in that region);
// in v11 QK reads K from REGISTERS — no LDS access between the sV writes and
// the sP barrier. Ordering proof with 2 barriers/iter:
//   sV writes(j) -> bar_C(j) -> PV reads(j)            (bar_C orders V and P)
//   PV reads(j) -> bar_A(j+1) -> sV writes(j+1)
//   sP[pb] writes(j) vs pf reads(j-2, same parity): 4 barriers apart
//   vr/kn prefetches are thread-private registers
// Everything else byte-identical to the 169.4us config: K-split QK^T with
// swapped-operand MFMA S^T, K direct-to-reg ping-pong, V in XOR-swizzled LDS,
// block-shared sP[2] P^T exchange (b64 writes), ones-MFMA row sums, XCD head
// clustering, heavy-first balanced tile map, __launch_bounds__(256,3).
// ---------------------------------------------------------------------------
__launch_bounds__(256, 3)
__global__ void attn_kernel(const __bf16* __restrict__ q_b, const __bf16* __restrict__ k_b,
                            const __bf16* __restrict__ vt_b, __bf16* __restrict__ ctx) {
  __shared__ __align__(16) __bf16 sV[64 * 64];      // [hd][kv] XOR-swizzled
  __shared__ __align__(16) __bf16 sP[2][64][72];    // block-shared dbuf P^T tile
  const int tid  = threadIdx.x;
  const int w    = tid >> 6, lane = tid & 63;
  const int quad = lane >> 4, lr = lane & 15;
  const int id = blockIdx.x;
  const int bh  = (id & 7) * 4 + ((id >> 3) & 3);   // XCD-clustered head
  const int t0i = (id >> 5) & 7;                    // slot within round
  const int rnd = id >> 8;                          // round 0..3 (heavy first)
  const int tq  = (3 - rnd) * 8 + ((rnd & 1) ? t0i : (7 - t0i));
  const __bf16* qh = q_b  + (size_t)bh * T_ * HD_;
  const __bf16* kh = k_b  + (size_t)bh * T_ * HD_;
  const __bf16* vh = vt_b + (size_t)bh * HD_ * T_;
  const int b = bh >> 4, h = bh & 15;

  const int r0 = tid >> 3, r1 = (tid + 256) >> 3;   // V staging rows (0..63)
  const int g0 = tid & 7;                           // chunk-in-row

  const int q0 = tq * 64;                           // block's 64-row Q tile
  const int nj = tq + 1;
  const int w16 = w * 16;

  bf16x8 qf[4][2];
#pragma unroll
  for (int qs = 0; qs < 4; ++qs)
#pragma unroll
    for (int ks = 0; ks < 2; ++ks)
      qf[qs][ks] = *(const bf16x8*)(qh + (size_t)(q0 + qs * 16 + lr) * HD_ + ks * 32 + quad * 8);

  bf16x8 onesf;
#pragma unroll
  for (int j = 0; j < 8; ++j) onesf[j] = (__bf16)1.0f;

  f32x4 o[4] = {};
  f32x4 ls = {};

  // K slice for this wave, iter 0 (direct to regs; ping-pong prefetched)
  const __bf16* kr = kh + (size_t)(w16 + lr) * HD_;
  bf16x8 kf0 = *(const bf16x8*)(kr + quad * 8);
  bf16x8 kf1 = *(const bf16x8*)(kr + 32 + quad * 8);
  bf16x8 kn0, kn1;

  // V tile j=0 prefetch into registers
  bf16x8 vr0 = *(const bf16x8*)(vh + (size_t)r0 * T_ + g0 * 8);
  bf16x8 vr1 = *(const bf16x8*)(vh + (size_t)r1 * T_ + g0 * 8);

  for (int j = 0; j < nj; ++j) {
    const int j0 = j * 64;
    const int pb = j & 1;
    __syncthreads();   // bar_A: all waves done with PV reads of sV (iter j-1)
    *(bf16x8*)(sV + r0 * 64 + (g0 ^ (r0 & 7)) * 8) = vr0;
    *(bf16x8*)(sV + r1 * 64 + (g0 ^ (r1 & 7)) * 8) = vr1;
    // (v10's bar_B removed: QK reads K from registers, not LDS; the sP
    //  barrier below also orders the sV writes before this iter's PV reads)
    if (j + 1 < nj) {   // overlap next-tile global loads with compute
      const int jn = j0 + 64;
      vr0 = *(const bf16x8*)(vh + (size_t)r0 * T_ + jn + g0 * 8);
      vr1 = *(const bf16x8*)(vh + (size_t)r1 * T_ + jn + g0 * 8);
      kn0 = *(const bf16x8*)(kr + (size_t)jn * HD_ + quad * 8);
      kn1 = *(const bf16x8*)(kr + (size_t)jn * HD_ + 32 + quad * 8);
    }
    // S^T = K (Q/8)^T for this wave's 16 kv rows x all 64 q (swapped MFMA)
    f32x4 ns[4] = {};
    __builtin_amdgcn_s_setprio(1);
#pragma unroll
    for (int qb = 0; qb < 4; ++qb) {
      ns[qb] = __builtin_amdgcn_mfma_f32_16x16x32_bf16(kf0, qf[qb][0], ns[qb], 0, 0, 0);
      ns[qb] = __builtin_amdgcn_mfma_f32_16x16x32_bf16(kf1, qf[qb][1], ns[qb], 0, 0, 0);
    }
    __builtin_amdgcn_s_setprio(0);
    if (j + 1 < nj) { kf0 = kn0; kf1 = kn1; }
    // causal mask (last j only): lane holds kv=j0+w16+quad*4+r, q=q0+qb*16+lr
    if (j0 + 63 > q0) {
      const int kvb = j0 + w16 + quad * 4;
#pragma unroll
      for (int qb = 0; qb < 4; ++qb) {
        const int qg = q0 + qb * 16 + lr;
#pragma unroll
        for (int r = 0; r < 4; ++r)
          if (kvb + r > qg) ns[qb][r] = -3.0e38f;
      }
    }
    // static-base softmax: P = exp(s)
#pragma unroll
    for (int qb = 0; qb < 4; ++qb)
#pragma unroll
      for (int r = 0; r < 4; ++r)
        ns[qb][r] = __expf(ns[qb][r]);
    // scatter P^T into block-shared sP: 4 kv-contiguous values -> b64 writes
#pragma unroll
    for (int qb = 0; qb < 4; ++qb) {
      bf16x4 pk;
#pragma unroll
      for (int r = 0; r < 4; ++r) pk[r] = (__bf16)ns[qb][r];
      *(bf16x4*)(&sP[pb][qb * 16 + lr][w16 + quad * 4]) = pk;
    }
    __syncthreads();   // bar_C: all waves' P columns AND sV writes visible
    bf16x8 pf[2];
#pragma unroll
    for (int ks = 0; ks < 2; ++ks)
      pf[ks] = *(const bf16x8*)(&sP[pb][w16 + lr][ks * 32 + quad * 8]);
    // O += P * V  (V^T from LDS: row = hd, cols = kv); row sums via ones-MFMA
    __builtin_amdgcn_s_setprio(1);
#pragma unroll
    for (int ni = 0; ni < 4; ++ni) {
      const int row = ni * 16 + lr;
#pragma unroll
      for (int ks = 0; ks < 2; ++ks) {
        const int ch = (ks * 4 + quad) ^ (row & 7);
        bf16x8 vf = *(const bf16x8*)(sV + row * 64 + ch * 8);
        o[ni] = __builtin_amdgcn_mfma_f32_16x16x32_bf16(pf[ks], vf, o[ni], 0, 0, 0);
      }
    }
    ls = __builtin_amdgcn_mfma_f32_16x16x32_bf16(pf[0], onesf, ls, 0, 0, 0);
    ls = __builtin_amdgcn_mfma_f32_16x16x32_bf16(pf[1], onesf, ls, 0, 0, 0);
    __builtin_amdgcn_s_setprio(0);
  }
  // normalize and store ctx in merged [b*T+t][h*64+d] layout (bf16).
  // ls[r] = rowsum for q = q0 + w16 + quad*4 + r (replicated over lr).
#pragma unroll
  for (int r = 0; r < 4; ++r) {
    const float inv = 1.0f / ls[r];
    const int t = q0 + w16 + quad * 4 + r;
#pragma unroll
    for (int ni = 0; ni < 4; ++ni)
      ctx[((size_t)(b * T_ + t)) * D_ + h * HD_ + ni * 16 + lr] =
          (__bf16)(o[ni][r] * inv);
  }
}

// ---------------------------------------------------------------------------
extern "C" void kernel_launch(void* const* d_in, const int* in_sizes, int n_in,
                              void* d_out, int out_size, void* d_ws, size_t ws_size,
                              hipStream_t stream) {
  (void)in_sizes; (void)n_in; (void)out_size; (void)ws_size;
  const float* x  = (const float*)d_in[0];
  const float* wq = (const float*)d_in[1];
  const float* wk = (const float*)d_in[2];
  const float* wv = (const float*)d_in[3];
  const float* wo = (const float*)d_in[4];
  const float* bo = (const float*)d_in[5];
  float* outp = (float*)d_out;

  char* ws = (char*)d_ws;
  __bf16* ctx    = (__bf16*)(ws + 0);           // [4096][1024] = 8 MB
  __bf16* wqkv_t = (__bf16*)(ws + 0);           // 3072x1024 = 6 MB (dead after gemm<0>)
  __bf16* wo_t   = (__bf16*)(ws + 8388608);     // 1024x1024 = 2 MB
  __bf16* q_b    = (__bf16*)(ws + 10485760);    // [2][16][2048][64] = 8 MB
  __bf16* k_b    = (__bf16*)(ws + 18874368);    // 8 MB
  __bf16* vt_b   = (__bf16*)(ws + 27262976);    // [2][16][64][2048] = 8 MB
  __bf16* xc     = (__bf16*)(ws + 35651584);    // canonical bf16 x = 8 MB

  prep_kernel<<<3072, 256, 0, stream>>>(x, wq, wk, wv, wo, xc, wqkv_t, wo_t);
  gemm128_kernel<0><<<768, 256, 0, stream>>>(xc, wqkv_t, 1024, q_b, k_b, vt_b, nullptr, nullptr);
  attn_kernel<<<1024, 256, 0, stream>>>(q_b, k_b, vt_b, ctx);
  gemm128_kernel<1><<<256, 256, 0, stream>>>(ctx, wo_t, 1024, nullptr, nullptr, nullptr, bo, outp);
}

// Round 15
// 166.323 us; speedup vs baseline: 4.4518x; 1.0186x over previous
//
#include <hip/hip_runtime.h>
#include <hip/hip_bf16.h>
#include <stdint.h>

// Problem constants: B=2, T=2048, D=1024, H=16, HD=64
#define B_  2
#define T_  2048
#define D_  1024
#define H_  16
#define HD_ 64

typedef __bf16 bf16x8 __attribute__((ext_vector_type(8)));
typedef __bf16 bf16x4 __attribute__((ext_vector_type(4)));
typedef float  f32x4  __attribute__((ext_vector_type(4)));

__device__ __forceinline__ void async_copy16(const void* g, void* l) {
  __builtin_amdgcn_global_load_lds((__attribute__((address_space(1))) void*)(g),
                                   (__attribute__((address_space(3))) void*)(l),
                                   16, 0, 0);
}

// ---------------------------------------------------------------------------
// Fused prep v2 (R10-measured):
//   blocks [0,1024):    transpose+convert the four 1024x1024 fp32 weights to
//                       bf16 (64x64 tiles, f32x4 reads, 128B coalesced writes)
//   blocks [1024,3072): convert x fp32 -> bf16, 8 elems/thread
// ---------------------------------------------------------------------------
__global__ void prep_kernel(const float* __restrict__ x,
                            const float* __restrict__ wq, const float* __restrict__ wk,
                            const float* __restrict__ wv, const float* __restrict__ wo,
                            __bf16* __restrict__ xc,
                            __bf16* __restrict__ wqkv_t, __bf16* __restrict__ wo_t) {
  const int id  = blockIdx.x;
  const int tid = threadIdx.x;
  if (id < 1024) {
    __shared__ __bf16 tile[64][68];                // pitch 68: 8B-aligned rows
    const int z   = id >> 8;                       // 0..3: wq,wk,wv,wo
    const int rem = id & 255;                      // 16x16 tiles of 64x64
    const int n0 = (rem & 15) * 64, k0 = (rem >> 4) * 64;
    const int kl = tid >> 4;                       // 0..15
    const int nn = (tid & 15) * 4;                 // 0,4,..,60
    const float* src = (z == 0) ? wq : (z == 1) ? wk : (z == 2) ? wv : wo;
    __bf16* dst = (z < 3) ? (wqkv_t + (size_t)z * 1024 * 1024) : wo_t;
#pragma unroll
    for (int it = 0; it < 4; ++it) {
      const int k = it * 16 + kl;
      const f32x4 v = *(const f32x4*)(src + (size_t)(k0 + k) * 1024 + n0 + nn);
      bf16x4 bv;
#pragma unroll
      for (int j = 0; j < 4; ++j) bv[j] = (__bf16)v[j];
      *(bf16x4*)&tile[k][nn] = bv;                 // 8B vector LDS write
    }
    __syncthreads();
#pragma unroll
    for (int it = 0; it < 4; ++it) {
      const int n = it * 16 + kl;                  // output row (n-index)
      bf16x4 bv;
#pragma unroll
      for (int j = 0; j < 4; ++j) bv[j] = tile[nn + j][n];
      // 16 lanes x 8B = 128B contiguous per output row
      *(bf16x4*)(dst + (size_t)(n0 + n) * 1024 + k0 + nn) = bv;
    }
  } else {
    const int i0 = ((id - 1024) * 256 + tid) * 8;
    const f32x4 f0 = *(const f32x4*)(x + i0);
    const f32x4 f1 = *(const f32x4*)(x + i0 + 4);
    bf16x8 v;
#pragma unroll
    for (int k = 0; k < 4; ++k) { v[k] = (__bf16)f0[k]; v[k + 4] = (__bf16)f1[k]; }
    *(bf16x8*)(xc + i0) = v;                       // 16B store
  }
}

// ---------------------------------------------------------------------------
// 128x128-tile bf16 MFMA GEMM — proven R5 structure (2-barrier, async
// global_load_lds staging, XOR swizzle, T1 XCD grid swizzle), upgraded from
// 4 waves to 8 WAVES PER BLOCK (512 threads, 2M x 4N, per-wave 64x32).
// R14 analysis: at 256thr the grid (768 = exactly 3 blocks/CU) capped the CU
// at 12 waves while VGPR (80 -> 6 waves/SIMD) and LDS (32KB -> 5 blocks)
// allow 24. Same grid, same per-block work/LDS/schedule; 2x resident waves.
// Per-wave regs DROP (acc 64->32 VGPR), staying under the 85-VGPR bound for
// 6 waves/SIMD. Staging: chunk = w*2+c (c<2), identical 0..15 coverage.
//   MODE 0: grid 768; each XCD owns 3 full B-panel columns (768KB < 4MB L2).
//   MODE 1: grid 256; each XCD sees full wo_t (2MB) + A chunk.
// MODE 0 epilogue scatters Q (x0.125) / K to [b,h,t,hd], V^T to [b,h,hd,t].
// MODE 1 epilogue adds bias (fp32), stores fp32 to out.
// ---------------------------------------------------------------------------
template <int MODE>
__launch_bounds__(512)
__global__ void gemm128_kernel(const __bf16* __restrict__ A, const __bf16* __restrict__ Bt, int K,
                               __bf16* __restrict__ q_b, __bf16* __restrict__ k_b,
                               __bf16* __restrict__ vt_b,
                               const float* __restrict__ bo, float* __restrict__ outp) {
  __shared__ __align__(16) __bf16 As[128 * 64];
  __shared__ __align__(16) __bf16 Bs[128 * 64];
  const int tid  = threadIdx.x;
  const int w    = tid >> 6, lane = tid & 63;      // w: 0..7
  const int quad = lane >> 4, lr = lane & 15;

  const int orig = blockIdx.x;
  int bx, by;
  if (MODE == 0) {
    const int wgid = (orig & 7) * 96 + (orig >> 3);   // 768 blocks
    bx = wgid >> 5;            // 0..23  (N columns, 3 per XCD)
    by = wgid & 31;            // 0..31
  } else {
    const int wgid = (orig & 7) * 32 + (orig >> 3);   // 256 blocks
    bx = wgid & 7;             // 0..7
    by = wgid >> 3;            // 0..31
  }
  const int tm = by * 128, tn = bx * 128;
  const int wm = (w >> 2) * 64, wn = (w & 3) * 32;  // 2M x 4N wave grid
  const int lrow   = lane >> 3;
  const int gchunk = (lane & 7) ^ lrow;

  f32x4 acc[4][2] = {};

  for (int k0 = 0; k0 < K; k0 += 64) {
#pragma unroll
    for (int c = 0; c < 2; ++c) {
      const int chunk = w * 2 + c;             // wave-uniform LDS base, 0..15
      const int row   = chunk * 8 + lrow;
      async_copy16(A  + (size_t)(tm + row) * K + k0 + gchunk * 8, As + chunk * 512);
      async_copy16(Bt + (size_t)(tn + row) * K + k0 + gchunk * 8, Bs + chunk * 512);
    }
    __syncthreads();
#pragma unroll
    for (int ks = 0; ks < 2; ++ks) {
      bf16x8 af[4], bfr[2];
#pragma unroll
      for (int mi = 0; mi < 4; ++mi) {
        const int row = wm + mi * 16 + lr;
        const int ch  = (ks * 4 + quad) ^ (row & 7);
        af[mi] = *(const bf16x8*)(As + row * 64 + ch * 8);
      }
#pragma unroll
      for (int ni = 0; ni < 2; ++ni) {
        const int row = wn + ni * 16 + lr;
        const int ch  = (ks * 4 + quad) ^ (row & 7);
        bfr[ni] = *(const bf16x8*)(Bs + row * 64 + ch * 8);
      }
#pragma unroll
      for (int mi = 0; mi < 4; ++mi)
#pragma unroll
        for (int ni = 0; ni < 2; ++ni)
          acc[mi][ni] = __builtin_amdgcn_mfma_f32_16x16x32_bf16(af[mi], bfr[ni], acc[mi][ni], 0, 0, 0);
    }
    __syncthreads();
  }

  if (MODE == 0) {
#pragma unroll
    for (int mi = 0; mi < 4; ++mi) {
      const int mrow0 = tm + wm + mi * 16 + quad * 4;
      const int b  = mrow0 >> 11;
      const int t0 = mrow0 & 2047;
#pragma unroll
      for (int ni = 0; ni < 2; ++ni) {
        const int ncol = tn + wn + ni * 16 + lr;
        const int mat  = ncol >> 10;
        const int nn   = ncol & 1023;
        const int h = nn >> 6, hd = nn & 63;
        if (mat == 0) {
#pragma unroll
          for (int r = 0; r < 4; ++r)
            q_b[((size_t)((b * H_ + h) * T_ + t0 + r)) * HD_ + hd] =
                (__bf16)(acc[mi][ni][r] * 0.125f);
        } else if (mat == 1) {
#pragma unroll
          for (int r = 0; r < 4; ++r)
            k_b[((size_t)((b * H_ + h) * T_ + t0 + r)) * HD_ + hd] =
                (__bf16)(acc[mi][ni][r]);
        } else {
          bf16x4 pk;
#pragma unroll
          for (int r = 0; r < 4; ++r) pk[r] = (__bf16)(acc[mi][ni][r]);
          *(bf16x4*)(vt_b + ((size_t)(b * H_ + h) * HD_ + hd) * T_ + t0) = pk;
        }
      }
    }
  } else {
#pragma unroll
    for (int mi = 0; mi < 4; ++mi) {
      const int m0 = tm + wm + mi * 16 + quad * 4;
#pragma unroll
      for (int ni = 0; ni < 2; ++ni) {
        const int n = tn + wn + ni * 16 + lr;
        const float bias = bo[n];
#pragma unroll
        for (int r = 0; r < 4; ++r)
          outp[(size_t)(m0 + r) * D_ + n] = acc[mi][ni][r] + bias;
      }
    }
  }
}

// ---------------------------------------------------------------------------
// Flash attention v15 (causal) — R14 code (169.42us, best measured).
// K-split QK^T (swapped-operand MFMA S^T), K direct-to-reg ping-pong, V in
// XOR-swizzled LDS, block-shared sP[2] P^T exchange (b64 writes), ones-MFMA
// row sums, 2 barriers/iter, XCD head clustering, balanced tile map.
// ---------------------------------------------------------------------------
__launch_bounds__(256, 3)
__global__ void attn_kernel(const __bf16* __restrict__ q_b, const __bf16* __restrict__ k_b,
                            const __bf16* __restrict__ vt_b, __bf16* __restrict__ ctx) {
  __shared__ __align__(16) __bf16 sV[64 * 64];      // [hd][kv] XOR-swizzled
  __shared__ __align__(16) __bf16 sP[2][64][72];    // block-shared dbuf P^T tile
  const int tid  = threadIdx.x;
  const int w    = tid >> 6, lane = tid & 63;
  const int quad = lane >> 4, lr = lane & 15;
  const int id = blockIdx.x;
  const int bh  = (id & 7) * 4 + ((id >> 3) & 3);   // XCD-clustered head
  const int t0i = (id >> 5) & 7;                    // slot within round
  const int rnd = id >> 8;                          // round 0..3 (heavy first)
  const int tq  = (3 - rnd) * 8 + ((rnd & 1) ? t0i : (7 - t0i));
  const __bf16* qh = q_b  + (size_t)bh * T_ * HD_;
  const __bf16* kh = k_b  + (size_t)bh * T_ * HD_;
  const __bf16* vh = vt_b + (size_t)bh * HD_ * T_;
  const int b = bh >> 4, h = bh & 15;

  const int r0 = tid >> 3, r1 = (tid + 256) >> 3;   // V staging rows (0..63)
  const int g0 = tid & 7;                           // chunk-in-row

  const int q0 = tq * 64;                           // block's 64-row Q tile
  const int nj = tq + 1;
  const int w16 = w * 16;

  bf16x8 qf[4][2];
#pragma unroll
  for (int qs = 0; qs < 4; ++qs)
#pragma unroll
    for (int ks = 0; ks < 2; ++ks)
      qf[qs][ks] = *(const bf16x8*)(qh + (size_t)(q0 + qs * 16 + lr) * HD_ + ks * 32 + quad * 8);

  bf16x8 onesf;
#pragma unroll
  for (int j = 0; j < 8; ++j) onesf[j] = (__bf16)1.0f;

  f32x4 o[4] = {};
  f32x4 ls = {};

  // K slice for this wave, iter 0 (direct to regs; ping-pong prefetched)
  const __bf16* kr = kh + (size_t)(w16 + lr) * HD_;
  bf16x8 kf0 = *(const bf16x8*)(kr + quad * 8);
  bf16x8 kf1 = *(const bf16x8*)(kr + 32 + quad * 8);
  bf16x8 kn0, kn1;

  // V tile j=0 prefetch into registers
  bf16x8 vr0 = *(const bf16x8*)(vh + (size_t)r0 * T_ + g0 * 8);
  bf16x8 vr1 = *(const bf16x8*)(vh + (size_t)r1 * T_ + g0 * 8);

  for (int j = 0; j < nj; ++j) {
    const int j0 = j * 64;
    const int pb = j & 1;
    __syncthreads();   // bar_A: all waves done with PV reads of sV (iter j-1)
    *(bf16x8*)(sV + r0 * 64 + (g0 ^ (r0 & 7)) * 8) = vr0;
    *(bf16x8*)(sV + r1 * 64 + (g0 ^ (r1 & 7)) * 8) = vr1;
    if (j + 1 < nj) {   // overlap next-tile global loads with compute
      const int jn = j0 + 64;
      vr0 = *(const bf16x8*)(vh + (size_t)r0 * T_ + jn + g0 * 8);
      vr1 = *(const bf16x8*)(vh + (size_t)r1 * T_ + jn + g0 * 8);
      kn0 = *(const bf16x8*)(kr + (size_t)jn * HD_ + quad * 8);
      kn1 = *(const bf16x8*)(kr + (size_t)jn * HD_ + 32 + quad * 8);
    }
    // S^T = K (Q/8)^T for this wave's 16 kv rows x all 64 q (swapped MFMA)
    f32x4 ns[4] = {};
    __builtin_amdgcn_s_setprio(1);
#pragma unroll
    for (int qb = 0; qb < 4; ++qb) {
      ns[qb] = __builtin_amdgcn_mfma_f32_16x16x32_bf16(kf0, qf[qb][0], ns[qb], 0, 0, 0);
      ns[qb] = __builtin_amdgcn_mfma_f32_16x16x32_bf16(kf1, qf[qb][1], ns[qb], 0, 0, 0);
    }
    __builtin_amdgcn_s_setprio(0);
    if (j + 1 < nj) { kf0 = kn0; kf1 = kn1; }
    // causal mask (last j only): lane holds kv=j0+w16+quad*4+r, q=q0+qb*16+lr
    if (j0 + 63 > q0) {
      const int kvb = j0 + w16 + quad * 4;
#pragma unroll
      for (int qb = 0; qb < 4; ++qb) {
        const int qg = q0 + qb * 16 + lr;
#pragma unroll
        for (int r = 0; r < 4; ++r)
          if (kvb + r > qg) ns[qb][r] = -3.0e38f;
      }
    }
    // static-base softmax: P = exp(s)
#pragma unroll
    for (int qb = 0; qb < 4; ++qb)
#pragma unroll
      for (int r = 0; r < 4; ++r)
        ns[qb][r] = __expf(ns[qb][r]);
    // scatter P^T into block-shared sP: 4 kv-contiguous values -> b64 writes
#pragma unroll
    for (int qb = 0; qb < 4; ++qb) {
      bf16x4 pk;
#pragma unroll
      for (int r = 0; r < 4; ++r) pk[r] = (__bf16)ns[qb][r];
      *(bf16x4*)(&sP[pb][qb * 16 + lr][w16 + quad * 4]) = pk;
    }
    __syncthreads();   // bar_C: all waves' P columns AND sV writes visible
    bf16x8 pf[2];
#pragma unroll
    for (int ks = 0; ks < 2; ++ks)
      pf[ks] = *(const bf16x8*)(&sP[pb][w16 + lr][ks * 32 + quad * 8]);
    // O += P * V  (V^T from LDS: row = hd, cols = kv); row sums via ones-MFMA
    __builtin_amdgcn_s_setprio(1);
#pragma unroll
    for (int ni = 0; ni < 4; ++ni) {
      const int row = ni * 16 + lr;
#pragma unroll
      for (int ks = 0; ks < 2; ++ks) {
        const int ch = (ks * 4 + quad) ^ (row & 7);
        bf16x8 vf = *(const bf16x8*)(sV + row * 64 + ch * 8);
        o[ni] = __builtin_amdgcn_mfma_f32_16x16x32_bf16(pf[ks], vf, o[ni], 0, 0, 0);
      }
    }
    ls = __builtin_amdgcn_mfma_f32_16x16x32_bf16(pf[0], onesf, ls, 0, 0, 0);
    ls = __builtin_amdgcn_mfma_f32_16x16x32_bf16(pf[1], onesf, ls, 0, 0, 0);
    __builtin_amdgcn_s_setprio(0);
  }
  // normalize and store ctx in merged [b*T+t][h*64+d] layout (bf16).
  // ls[r] = rowsum for q = q0 + w16 + quad*4 + r (replicated over lr).
#pragma unroll
  for (int r = 0; r < 4; ++r) {
    const float inv = 1.0f / ls[r];
    const int t = q0 + w16 + quad * 4 + r;
#pragma unroll
    for (int ni = 0; ni < 4; ++ni)
      ctx[((size_t)(b * T_ + t)) * D_ + h * HD_ + ni * 16 + lr] =
          (__bf16)(o[ni][r] * inv);
  }
}

// ---------------------------------------------------------------------------
extern "C" void kernel_launch(void* const* d_in, const int* in_sizes, int n_in,
                              void* d_out, int out_size, void* d_ws, size_t ws_size,
                              hipStream_t stream) {
  (void)in_sizes; (void)n_in; (void)out_size; (void)ws_size;
  const float* x  = (const float*)d_in[0];
  const float* wq = (const float*)d_in[1];
  const float* wk = (const float*)d_in[2];
  const float* wv = (const float*)d_in[3];
  const float* wo = (const float*)d_in[4];
  const float* bo = (const float*)d_in[5];
  float* outp = (float*)d_out;

  char* ws = (char*)d_ws;
  __bf16* ctx    = (__bf16*)(ws + 0);           // [4096][1024] = 8 MB
  __bf16* wqkv_t = (__bf16*)(ws + 0);           // 3072x1024 = 6 MB (dead after gemm<0>)
  __bf16* wo_t   = (__bf16*)(ws + 8388608);     // 1024x1024 = 2 MB
  __bf16* q_b    = (__bf16*)(ws + 10485760);    // [2][16][2048][64] = 8 MB
  __bf16* k_b    = (__bf16*)(ws + 18874368);    // 8 MB
  __bf16* vt_b   = (__bf16*)(ws + 27262976);    // [2][16][64][2048] = 8 MB
  __bf16* xc     = (__bf16*)(ws + 35651584);    // canonical bf16 x = 8 MB

  prep_kernel<<<3072, 256, 0, stream>>>(x, wq, wk, wv, wo, xc, wqkv_t, wo_t);
  gemm128_kernel<0><<<768, 512, 0, stream>>>(xc, wqkv_t, 1024, q_b, k_b, vt_b, nullptr, nullptr);
  attn_kernel<<<1024, 256, 0, stream>>>(q_b, k_b, vt_b, ctx);
  gemm128_kernel<1><<<256, 512, 0, stream>>>(ctx, wo_t, 1024, nullptr, nullptr, nullptr, bo, outp);
}